// Round 1
// baseline (198.308 us; speedup 1.0000x reference)
//
#include <hip/hip_runtime.h>
#include <math.h>

#define IN_DIM 256
#define NH 4
#define DQK 8
#define ATH 64
#define NB 2
#define NSP 4096  // 64*64

#define QKV_STRIDE ((size_t)NB * NH * NSP * DQK)  // 262144 floats per tensor

// ---------------------------------------------------------------------------
// K1: fused q/k/v 1x1-conv projection.
// grid (32, NH, NB), block 128. One thread per (b,h,n); 24 accumulators.
// Weight reads are wave-uniform -> compiler scalarizes to s_load (K$).
// x reads coalesced across lanes (lane -> n).
// ---------------------------------------------------------------------------
__global__ __launch_bounds__(128) void qkv_kernel(
    const float* __restrict__ x,
    const float* __restrict__ Wq, const float* __restrict__ bq,
    const float* __restrict__ Wk, const float* __restrict__ bk,
    const float* __restrict__ Wv, const float* __restrict__ bv,
    float* __restrict__ ws)
{
    const int n = blockIdx.x * 128 + threadIdx.x;
    const int h = blockIdx.y;
    const int b = blockIdx.z;

    float accq[DQK], acck[DQK], accv[DQK];
#pragma unroll
    for (int d = 0; d < DQK; ++d) {
        accq[d] = bq[h * DQK + d];
        acck[d] = bk[h * DQK + d];
        accv[d] = bv[h * DQK + d];
    }

    const float* xb = x + (size_t)b * IN_DIM * NSP + n;
    const float* wq = Wq + h * DQK * IN_DIM;
    const float* wk = Wk + h * DQK * IN_DIM;
    const float* wv = Wv + h * DQK * IN_DIM;

#pragma unroll 4
    for (int c = 0; c < IN_DIM; ++c) {
        const float xv = xb[(size_t)c * NSP];
#pragma unroll
        for (int d = 0; d < DQK; ++d) {
            accq[d] = fmaf(wq[d * IN_DIM + c], xv, accq[d]);
            acck[d] = fmaf(wk[d * IN_DIM + c], xv, acck[d]);
            accv[d] = fmaf(wv[d * IN_DIM + c], xv, accv[d]);
        }
    }

    const size_t base = ((size_t)(b * NH + h) * NSP + n) * DQK;
    float4* qp = (float4*)(ws + base);
    float4* kp = (float4*)(ws + QKV_STRIDE + base);
    float4* vp = (float4*)(ws + 2 * QKV_STRIDE + base);
    qp[0] = make_float4(accq[0], accq[1], accq[2], accq[3]);
    qp[1] = make_float4(accq[4], accq[5], accq[6], accq[7]);
    kp[0] = make_float4(acck[0], acck[1], acck[2], acck[3]);
    kp[1] = make_float4(acck[4], acck[5], acck[6], acck[7]);
    vp[0] = make_float4(accv[0], accv[1], accv[2], accv[3]);
    vp[1] = make_float4(accv[4], accv[5], accv[6], accv[7]);
}

__device__ __forceinline__ float dot8(const float4 a0, const float4 a1,
                                      const float4 b0, const float4 b1)
{
    float s = a0.x * b0.x;
    s = fmaf(a0.y, b0.y, s);
    s = fmaf(a0.z, b0.z, s);
    s = fmaf(a0.w, b0.w, s);
    s = fmaf(a1.x, b1.x, s);
    s = fmaf(a1.y, b1.y, s);
    s = fmaf(a1.z, b1.z, s);
    s = fmaf(a1.w, b1.w, s);
    return s;
}

__device__ __forceinline__ void fma4(float4& acc, const float e, const float4 v)
{
    acc.x = fmaf(e, v.x, acc.x);
    acc.y = fmaf(e, v.y, acc.y);
    acc.z = fmaf(e, v.z, acc.z);
    acc.w = fmaf(e, v.w, acc.w);
}

// ---------------------------------------------------------------------------
// K2: streaming "transposed-flash" attention + fused epilogue.
// For each column m: o[d,m] = sum_n v[d,n] e^{q[:,n]·k[:,m]} / sum_n e^{...}
// (scores |s| <~ 3, so no max-subtraction needed for fp32 stability).
// grid (32 mtiles, 8 bh), block 512 = 8 waves.
//   wave w streams n in [w*512, w*512+512); lane owns columns m0=lane, m1=lane+64
//   of the block's 128-column tile. q/v rows staged in per-wave LDS tiles
//   (broadcast ds_read_b128 reads, conflict-free), k-vec + acc in registers.
// Cross-wave combine via LDS, then fused Wo + bias + gamma + residual.
// ---------------------------------------------------------------------------
__global__ __launch_bounds__(512) void attn_kernel(
    const float* __restrict__ ws,
    const float* __restrict__ x,
    const float* __restrict__ Wo, const float* __restrict__ bo,
    const float* __restrict__ gamma,
    float* __restrict__ out)
{
    // LDS union: phase A staging (32 KB) / phase B reduction (40.5 KB)
    __shared__ __align__(16) unsigned char smem[41472];
    float4* sQ = (float4*)smem;            // [8][64][2] = 16 KB
    float4* sV = (float4*)(smem + 16384);  // [8][64][2] = 16 KB
    float* sRed = (float*)smem;            // [8][128][9] = 36864 B
    float* sSum = (float*)(smem + 36864);  // [128][9]    = 4608 B

    const int tid = threadIdx.x;
    const int w = tid >> 6;    // wave 0..7
    const int lane = tid & 63;
    const int mtile = blockIdx.x;  // 0..31, 128 columns each
    const int bh = blockIdx.y;     // 0..7
    const int h = bh & (NH - 1);
    const int b = bh >> 2;

    const float* qg = ws + (size_t)bh * NSP * DQK;
    const float* kg = ws + QKV_STRIDE + (size_t)bh * NSP * DQK;
    const float* vg = ws + 2 * QKV_STRIDE + (size_t)bh * NSP * DQK;

    const int m0 = mtile * 128 + lane;
    const int m1 = m0 + 64;
    const float4 k0a = *(const float4*)(kg + (size_t)m0 * DQK);
    const float4 k0b = *(const float4*)(kg + (size_t)m0 * DQK + 4);
    const float4 k1a = *(const float4*)(kg + (size_t)m1 * DQK);
    const float4 k1b = *(const float4*)(kg + (size_t)m1 * DQK + 4);

    float4 acc0a = {0.f, 0.f, 0.f, 0.f}, acc0b = {0.f, 0.f, 0.f, 0.f};
    float4 acc1a = {0.f, 0.f, 0.f, 0.f}, acc1b = {0.f, 0.f, 0.f, 0.f};
    float l0 = 0.f, l1 = 0.f;

    const int n0 = w * 512;

    // prefetch tile 0
    int n = n0 + lane;
    float4 qa = *(const float4*)(qg + (size_t)n * DQK);
    float4 qb = *(const float4*)(qg + (size_t)n * DQK + 4);
    float4 va = *(const float4*)(vg + (size_t)n * DQK);
    float4 vb = *(const float4*)(vg + (size_t)n * DQK + 4);

    for (int t = 0; t < 8; ++t) {
        __syncthreads();  // WAR: previous tile's LDS reads complete everywhere
        const int sidx = (w * 64 + lane) * 2;
        sQ[sidx] = qa; sQ[sidx + 1] = qb;
        sV[sidx] = va; sV[sidx + 1] = vb;
        __syncthreads();  // RAW: tile visible

        if (t < 7) {  // prefetch next tile before compute to hide latency
            n = n0 + (t + 1) * 64 + lane;
            qa = *(const float4*)(qg + (size_t)n * DQK);
            qb = *(const float4*)(qg + (size_t)n * DQK + 4);
            va = *(const float4*)(vg + (size_t)n * DQK);
            vb = *(const float4*)(vg + (size_t)n * DQK + 4);
        }

        const float4* qrow = sQ + w * 128;
        const float4* vrow = sV + w * 128;
#pragma unroll 4
        for (int i = 0; i < 64; ++i) {
            const float4 q0 = qrow[i * 2];
            const float4 q1 = qrow[i * 2 + 1];
            const float4 v0 = vrow[i * 2];
            const float4 v1 = vrow[i * 2 + 1];
            const float s0 = dot8(q0, q1, k0a, k0b);
            const float s1 = dot8(q0, q1, k1a, k1b);
            const float e0 = __expf(s0);
            const float e1 = __expf(s1);
            l0 += e0; l1 += e1;
            fma4(acc0a, e0, v0); fma4(acc0b, e0, v1);
            fma4(acc1a, e1, v0); fma4(acc1b, e1, v1);
        }
    }

    __syncthreads();  // all waves done reading staging LDS before reuse as sRed

    {
        float* r0 = sRed + ((size_t)w * 128 + lane) * 9;
        r0[0] = acc0a.x; r0[1] = acc0a.y; r0[2] = acc0a.z; r0[3] = acc0a.w;
        r0[4] = acc0b.x; r0[5] = acc0b.y; r0[6] = acc0b.z; r0[7] = acc0b.w;
        r0[8] = l0;
        float* r1 = sRed + ((size_t)w * 128 + lane + 64) * 9;
        r1[0] = acc1a.x; r1[1] = acc1a.y; r1[2] = acc1a.z; r1[3] = acc1a.w;
        r1[4] = acc1b.x; r1[5] = acc1b.y; r1[6] = acc1b.z; r1[7] = acc1b.w;
        r1[8] = l1;
    }
    __syncthreads();

    // reduce 8 waves -> sSum[128][9]
    for (int idx = tid; idx < 128 * 9; idx += 512) {
        float s = 0.f;
#pragma unroll
        for (int ww = 0; ww < 8; ++ww) s += sRed[ww * 128 * 9 + idx];
        sSum[idx] = s;
    }
    __syncthreads();

    // epilogue: y[e,m] = gamma*(Wo[e,:]·(o/l) + bo[e]) + x
    const int m = tid & 127;
    const int eg = tid >> 7;  // 0..3, 16 channels each
    const float rl = 1.0f / sSum[m * 9 + 8];
    float od[DQK];
#pragma unroll
    for (int d = 0; d < DQK; ++d) od[d] = sSum[m * 9 + d] * rl;

    const int mg = mtile * 128 + m;
    const float g = gamma[h];
#pragma unroll
    for (int e = eg * 16; e < eg * 16 + 16; ++e) {
        const float* wo = Wo + (h * ATH + e) * DQK;
        float y = bo[h * ATH + e];
#pragma unroll
        for (int d = 0; d < DQK; ++d) y = fmaf(wo[d], od[d], y);
        const size_t oi = ((size_t)(b * IN_DIM + h * ATH + e)) * NSP + mg;
        out[oi] = fmaf(g, y, x[oi]);
    }
}

extern "C" void kernel_launch(void* const* d_in, const int* in_sizes, int n_in,
                              void* d_out, int out_size, void* d_ws, size_t ws_size,
                              hipStream_t stream)
{
    const float* x = (const float*)d_in[0];
    const float* Wq = (const float*)d_in[1];
    const float* bq = (const float*)d_in[2];
    const float* Wk = (const float*)d_in[3];
    const float* bk = (const float*)d_in[4];
    const float* Wv = (const float*)d_in[5];
    const float* bv = (const float*)d_in[6];
    const float* Wo = (const float*)d_in[7];
    const float* bo = (const float*)d_in[8];
    const float* gamma = (const float*)d_in[9];
    float* out = (float*)d_out;
    float* ws = (float*)d_ws;  // needs 3 MB: q,k,v each [B*NH][N][8] fp32

    qkv_kernel<<<dim3(NSP / 128, NH, NB), 128, 0, stream>>>(
        x, Wq, bq, Wk, bk, Wv, bv, ws);
    attn_kernel<<<dim3(32, NB * NH), 512, 0, stream>>>(
        ws, x, Wo, bo, gamma, out);
}

// Round 2
// 131.552 us; speedup vs baseline: 1.5075x; 1.5075x over previous
//
#include <hip/hip_runtime.h>
#include <hip/hip_bf16.h>

#define IN_DIM 256
#define NH 4
#define DQK 8
#define ATH 64
#define NB 2
#define NSP 4096  // 64*64
#define LOG2E 1.44269504088896f
#define LN2 0.6931471805599453f

typedef __attribute__((ext_vector_type(8))) short short8;
typedef __attribute__((ext_vector_type(16))) float f32x16;

// ws byte layout:
//   Q_OFF: q bf16 [8 bh][4096 n][8]  (A-frag rows, 16 B each)   512 KB
//   K_OFF: k bf16 [8 bh][4096 m][8]  (B-frag rows, pre-scaled by log2e) 512 KB
//   V_OFF: v B-frags bf16 [8 bh][128 T][2 c][64 lane][8]        2 MB
//          (lane = 32*h' + e; elem j -> n = 32T+16c+8h'+j, col e; e=8 is ones)
//   P_OFF: partials f32 [8 bh][128 mt][4 nq][18 (h'*9+e)][16 r] ~4.7 MB
#define Q_OFF 0
#define K_OFF (512u * 1024u)
#define V_OFF (1024u * 1024u)
#define P_OFF (3u * 1024u * 1024u)

__device__ __forceinline__ float fast_exp2(float x) {
#if __has_builtin(__builtin_amdgcn_exp2f)
    return __builtin_amdgcn_exp2f(x);
#else
    return __expf(x * LN2);
#endif
}

__device__ __forceinline__ unsigned short f2bf(float f) {
    __hip_bfloat16 t = __float2bfloat16(f);
    return *(unsigned short*)&t;
}

// ---------------------------------------------------------------------------
// K1: qkv projection. 1 wave/block; block = 64 n for one (b, h, sel).
// grid (64 ntiles, 12 = 4h*3sel, 2 b) = 1536 waves -> 6 waves/CU.
// Weights wave-uniform -> s_load; x coalesced. Writes MFMA-ready layouts.
// ---------------------------------------------------------------------------
__global__ __launch_bounds__(64, 4) void qkv_kernel(
    const float* __restrict__ x,
    const float* __restrict__ Wq, const float* __restrict__ bq,
    const float* __restrict__ Wk, const float* __restrict__ bk,
    const float* __restrict__ Wv, const float* __restrict__ bv,
    unsigned char* __restrict__ ws)
{
    const int n = blockIdx.x * 64 + threadIdx.x;
    const int g = blockIdx.y;          // 0..11
    const int b = blockIdx.z;
    const int h = g / 3, sel = g % 3;

    const float* W = (sel == 0) ? Wq : (sel == 1) ? Wk : Wv;
    const float* bias = (sel == 0) ? bq : (sel == 1) ? bk : bv;

    float acc[DQK];
#pragma unroll
    for (int d = 0; d < DQK; ++d) acc[d] = bias[h * DQK + d];

    const float* xb = x + (size_t)b * IN_DIM * NSP + n;
    const float* Wh = W + h * DQK * IN_DIM;

#pragma unroll 8
    for (int c = 0; c < IN_DIM; ++c) {
        const float xv = xb[(size_t)c * NSP];
#pragma unroll
        for (int d = 0; d < DQK; ++d)
            acc[d] = fmaf(Wh[d * IN_DIM + c], xv, acc[d]);
    }

    const int bh = b * NH + h;
    if (sel == 2) {
        // v in B-frag layout + ones column (e=8)
        const int T = n >> 5, c2 = (n >> 4) & 1, h2 = (n >> 3) & 1, j = n & 7;
        unsigned char* base = ws + V_OFF + (size_t)bh * 262144u +
                              ((size_t)((T * 2 + c2) * 64 + 32 * h2) * 16) + j * 2;
#pragma unroll
        for (int e = 0; e < 8; ++e)
            *(unsigned short*)(base + e * 16) = f2bf(acc[e]);
        *(unsigned short*)(base + 8 * 16) = 0x3F80;  // bf16 1.0
    } else {
        const float scale = (sel == 1) ? LOG2E : 1.0f;  // fold log2e into k
        unsigned short r[8];
#pragma unroll
        for (int d = 0; d < DQK; ++d) r[d] = f2bf(acc[d] * scale);
        uint4 pk;
        pk.x = (unsigned)r[0] | ((unsigned)r[1] << 16);
        pk.y = (unsigned)r[2] | ((unsigned)r[3] << 16);
        pk.z = (unsigned)r[4] | ((unsigned)r[5] << 16);
        pk.w = (unsigned)r[6] | ((unsigned)r[7] << 16);
        unsigned char* base = ws + ((sel == 0) ? Q_OFF : K_OFF) +
                              ((size_t)bh * NSP + n) * 16;
        *(uint4*)base = pk;
    }
}

// ---------------------------------------------------------------------------
// K2: MFMA flash attention (transposed softmax), partial over n-quarters.
// 1 wave per (m-tile, bh, nq): grid (128, 8, 4) = 4096 waves = 4/SIMD.
// Per 32n-tile: S^T = mfma(q, k) [d pad 16]; exp2; pack bf16; xor-32 shuffle
// to A-layout; 2 PV mfma into 16-f32 acc (col e=8 accumulates l via ones).
// Barrier-free, LDS-free main loop.
// ---------------------------------------------------------------------------
__global__ __launch_bounds__(64, 4) void attn_partial(unsigned char* __restrict__ ws)
{
    const int lane = threadIdx.x;
    const int mt = blockIdx.x;   // 0..127
    const int bh = blockIdx.y;   // 0..7
    const int nq = blockIdx.z;   // 0..3
    const int e = lane & 31;
    const int hp = lane >> 5;

    union U4 { uint4 u; short8 s; };
    const uint4 zero4 = make_uint4(0, 0, 0, 0);

    U4 kf;
    kf.u = (hp == 0)
        ? *(const uint4*)(ws + K_OFF + ((size_t)bh * NSP + mt * 32 + e) * 16)
        : zero4;

    const uint4* qrows = (const uint4*)(ws + Q_OFF + (size_t)bh * NSP * 16);
    const uint4* vfr = (const uint4*)(ws + V_OFF + (size_t)bh * 262144u);

    f32x16 acc = {};
    const f32x16 zc = {};

    const int nt0 = nq * 32;
    U4 qf_n, vf0_n, vf1_n;
    qf_n.u = (hp == 0) ? qrows[nt0 * 32 + e] : zero4;
    vf0_n.u = vfr[(nt0 * 2 + 0) * 64 + lane];
    vf1_n.u = vfr[(nt0 * 2 + 1) * 64 + lane];

    for (int t = 0; t < 32; ++t) {
        U4 qf = qf_n, vf0 = vf0_n, vf1 = vf1_n;
        if (t < 31) {  // software prefetch next tile
            const int nt = nt0 + t + 1;
            qf_n.u = (hp == 0) ? qrows[nt * 32 + e] : zero4;
            vf0_n.u = vfr[(nt * 2 + 0) * 64 + lane];
            vf1_n.u = vfr[(nt * 2 + 1) * 64 + lane];
        }

        // S^T[n,m] (D-layout: lane holds col m=e, 16 rows n)
        f32x16 S = __builtin_amdgcn_mfma_f32_32x32x16_bf16(qf.s, kf.s, zc, 0, 0, 0);

        // exp2 (k pre-scaled) + pack to bf16 pairs; Qd[2g..2g+1] = quad g
        unsigned int Qd[8];
#pragma unroll
        for (int i = 0; i < 8; ++i) {
            const float a = fast_exp2(S[2 * i]);
            const float b2 = fast_exp2(S[2 * i + 1]);
            Qd[i] = (unsigned)f2bf(a) | ((unsigned)f2bf(b2) << 16);
        }

        // xor-32 exchange: build A-layout frags (rows m=lane&31, k=n)
        const int sA0 = hp ? Qd[0] : Qd[2];
        const int sA1 = hp ? Qd[1] : Qd[3];
        const int rA0 = __shfl_xor(sA0, 32, 64);
        const int rA1 = __shfl_xor(sA1, 32, 64);
        const int sB0 = hp ? Qd[4] : Qd[6];
        const int sB1 = hp ? Qd[5] : Qd[7];
        const int rB0 = __shfl_xor(sB0, 32, 64);
        const int rB1 = __shfl_xor(sB1, 32, 64);

        U4 f0, f1;
        f0.u = hp ? make_uint4(rA0, rA1, Qd[2], Qd[3])
                  : make_uint4(Qd[0], Qd[1], rA0, rA1);
        f1.u = hp ? make_uint4(rB0, rB1, Qd[6], Qd[7])
                  : make_uint4(Qd[4], Qd[5], rB0, rB1);

        acc = __builtin_amdgcn_mfma_f32_32x32x16_bf16(f0.s, vf0.s, acc, 0, 0, 0);
        acc = __builtin_amdgcn_mfma_f32_32x32x16_bf16(f1.s, vf1.s, acc, 0, 0, 0);
    }

    // store partial: only cols e<=8 meaningful (8 o-channels + l at e=8)
    if (e <= 8) {
        float* pp = (float*)(ws + P_OFF) +
                    ((((size_t)bh * 128 + mt) * 4 + nq) * 18 + hp * 9 + e) * 16;
#pragma unroll
        for (int r = 0; r < 16; ++r) pp[r] = acc[r];
    }
}

// ---------------------------------------------------------------------------
// K3: epilogue. grid (32 mstrips, 8 bh), block 256.
// Sum 4 n-quarter partials -> o[128 m][9] in LDS, then y = gamma*(Wo·(o/l)+bo)+x.
// ---------------------------------------------------------------------------
__global__ __launch_bounds__(256) void attn_epilogue(
    const unsigned char* __restrict__ ws,
    const float* __restrict__ x,
    const float* __restrict__ Wo, const float* __restrict__ bo,
    const float* __restrict__ gamma,
    float* __restrict__ out)
{
    __shared__ float sO[128 * 13];  // stride 13 (odd) -> conflict-light
    const int tid = threadIdx.x;
    const int ms = blockIdx.x;   // 0..31
    const int bh = blockIdx.y;   // 0..7
    const int h = bh & (NH - 1);
    const int b = bh >> 2;

    const float* P = (const float*)(ws + P_OFF);
    for (int idx = tid; idx < 128 * 9; idx += 256) {
        const int m_l = idx / 9, e = idx % 9;
        const int mt = ms * 4 + (m_l >> 5);
        const int m32 = m_l & 31;
        const int hp = (m32 >> 2) & 1;
        const int r = (m32 & 3) + 4 * (m32 >> 3);
        const size_t base = ((((size_t)bh * 128 + mt) * 4) * 18 + hp * 9 + e) * 16 + r;
        const float s = P[base] + P[base + 18 * 16] +
                        P[base + 2 * 18 * 16] + P[base + 3 * 18 * 16];
        sO[m_l * 13 + e] = s;
    }
    __syncthreads();

    const int m_l = tid & 127;
    const int half = tid >> 7;
    const float rl = 1.0f / sO[m_l * 13 + 8];
    float od[DQK];
#pragma unroll
    for (int d = 0; d < DQK; ++d) od[d] = sO[m_l * 13 + d] * rl;

    const float g = gamma[h];
    const int mg = ms * 128 + m_l;
#pragma unroll
    for (int eo = half * 32; eo < half * 32 + 32; ++eo) {
        const float* wo = Wo + (h * ATH + eo) * DQK;
        float y = bo[h * ATH + eo];
#pragma unroll
        for (int d = 0; d < DQK; ++d) y = fmaf(wo[d], od[d], y);
        const size_t oi = ((size_t)(b * IN_DIM) + h * ATH + eo) * NSP + mg;
        out[oi] = fmaf(g, y, x[oi]);
    }
}

extern "C" void kernel_launch(void* const* d_in, const int* in_sizes, int n_in,
                              void* d_out, int out_size, void* d_ws, size_t ws_size,
                              hipStream_t stream)
{
    const float* x = (const float*)d_in[0];
    const float* Wq = (const float*)d_in[1];
    const float* bq = (const float*)d_in[2];
    const float* Wk = (const float*)d_in[3];
    const float* bk = (const float*)d_in[4];
    const float* Wv = (const float*)d_in[5];
    const float* bv = (const float*)d_in[6];
    const float* Wo = (const float*)d_in[7];
    const float* bo = (const float*)d_in[8];
    const float* gamma = (const float*)d_in[9];
    float* out = (float*)d_out;
    unsigned char* ws = (unsigned char*)d_ws;  // needs ~7.8 MB

    qkv_kernel<<<dim3(NSP / 64, 12, NB), 64, 0, stream>>>(
        x, Wq, bq, Wk, bk, Wv, bv, ws);
    attn_partial<<<dim3(128, NB * NH, 4), 64, 0, stream>>>(ws);
    attn_epilogue<<<dim3(32, NB * NH), 256, 0, stream>>>(
        ws, x, Wo, bo, gamma, out);
}

// Round 3
// 119.916 us; speedup vs baseline: 1.6537x; 1.0970x over previous
//
#include <hip/hip_runtime.h>
#include <hip/hip_bf16.h>

#define IN_DIM 256
#define NH 4
#define DQK 8
#define ATH 64
#define NB 2
#define NSP 4096  // 64*64
#define LOG2E 1.44269504088896f

typedef __attribute__((ext_vector_type(8))) short short8;
typedef __attribute__((ext_vector_type(16))) float f32x16;

// ws byte layout:
//   Q_OFF : q rows bf16 [8 bh][4096 n][8d]                     512 KB
//   K_OFF : k rows bf16 [8 bh][4096 m][8d] (pre-scaled log2e)  512 KB
//   VR_OFF: v rows bf16 [8 bh][4096 n][8d]                     512 KB
//   VF_OFF: v B-frags bf16 [8 bh][128 T][2 c2][64 lane][8j]    2 MB
//           (lane = 32*h2 + e; elem j -> n = 32T+16c2+8h2+j, col e; e=8 ones)
//   P_OFF : partials f32 [8 bh][128 mt][4 nq][18 (h2*9+e)][16 r] ~4.7 MB
#define Q_OFF 0u
#define K_OFF (512u * 1024u)
#define VR_OFF (1024u * 1024u)
#define VF_OFF (1536u * 1024u)
#define P_OFF (3584u * 1024u)

__device__ __forceinline__ float fast_exp2(float x) {
#if __has_builtin(__builtin_amdgcn_exp2f)
    return __builtin_amdgcn_exp2f(x);
#else
    return exp2f(x);
#endif
}

// round-to-nearest-even fp32->bf16 (inputs are finite, no NaN handling needed)
__device__ __forceinline__ unsigned bf_rne(float f) {
    unsigned u = __float_as_uint(f);
    u += 0x7FFFu + ((u >> 16) & 1u);
    return u >> 16;
}
__device__ __forceinline__ unsigned pack2bf(float a, float b) {
    return bf_rne(a) | (bf_rne(b) << 16);
}
// truncation pack (used only for softmax P: bias cancels in P/sum(P))
__device__ __forceinline__ unsigned pack2bf_tr(float a, float b) {
    return (__float_as_uint(a) >> 16) | (__float_as_uint(b) & 0xFFFF0000u);
}

// ---------------------------------------------------------------------------
// K1: qkv as one MFMA GEMM. D[96,4096] = Wcat[96,256] x[256,4096] per b.
// Rows R: h = R/24, sel = (R%24)/8 (0=q,1=k,2=v), d = R%8.
// grid (128 n-tiles, 3 m-tiles, 2 b) = 768 waves, 16 MFMAs each.
// Epilogue: +bias, k*log2e, xor-32 repack -> coalesced 16B row stores.
// ---------------------------------------------------------------------------
__global__ __launch_bounds__(64) void qkv_gemm(
    const float* __restrict__ x,
    const float* __restrict__ Wq, const float* __restrict__ bq,
    const float* __restrict__ Wk, const float* __restrict__ bk,
    const float* __restrict__ Wv, const float* __restrict__ bv,
    unsigned char* __restrict__ ws)
{
    const int lane = threadIdx.x;
    const int nt = blockIdx.x;   // 0..127
    const int mt = blockIdx.y;   // 0..2
    const int b  = blockIdx.z;   // 0..1
    const int col = lane & 31;
    const int hp  = lane >> 5;

    // this lane's A-row of Wcat
    const int R = mt * 32 + col;
    const int h = R / 24;
    const int r24 = R % 24;
    const int sel = r24 >> 3;
    const int dd = r24 & 7;
    const float* Wsel = (sel == 0) ? Wq : (sel == 1) ? Wk : Wv;
    const float* wrow = Wsel + (h * DQK + dd) * IN_DIM;

    // x column base: c = kt*16 + hp*8 + j, n = nt*32 + col
    const float* xb = x + (size_t)b * IN_DIM * NSP + (size_t)(hp * 8) * NSP + nt * 32 + col;

    union U4 { uint4 u; short8 s; };
    f32x16 acc = {};

#pragma unroll
    for (int kt = 0; kt < 16; ++kt) {
        const float4 wa = *(const float4*)(wrow + kt * 16 + hp * 8);
        const float4 wb = *(const float4*)(wrow + kt * 16 + hp * 8 + 4);
        U4 af;
        af.u.x = pack2bf(wa.x, wa.y);
        af.u.y = pack2bf(wa.z, wa.w);
        af.u.z = pack2bf(wb.x, wb.y);
        af.u.w = pack2bf(wb.z, wb.w);

        float xv[8];
#pragma unroll
        for (int j = 0; j < 8; ++j) xv[j] = xb[(size_t)(kt * 16 + j) * NSP];
        U4 bfm;
        bfm.u.x = pack2bf(xv[0], xv[1]);
        bfm.u.y = pack2bf(xv[2], xv[3]);
        bfm.u.z = pack2bf(xv[4], xv[5]);
        bfm.u.w = pack2bf(xv[6], xv[7]);

        acc = __builtin_amdgcn_mfma_f32_32x32x16_bf16(af.s, bfm.s, acc, 0, 0, 0);
    }

    // epilogue: rows m = (reg&3) + 8*(reg>>2) + 4*hp. Row-group g (m=8g..8g+7)
    // = regs 4g..4g+3; one (h,sel) per group. Pair groups, xor-32 to assemble
    // full 8-d rows: hp0 stores group gA's row, hp1 stores gB's.
    const int n = nt * 32 + col;
#pragma unroll
    for (int p = 0; p < 2; ++p) {
        const int gA = 2 * p, gB = 2 * p + 1;
        const int RA = mt * 32 + 8 * gA, RB = mt * 32 + 8 * gB;
        const int hA = RA / 24, hB = RB / 24;
        const int selA = (RA % 24) >> 3, selB = (RB % 24) >> 3;
        const float* bsA = (selA == 0) ? bq : (selA == 1) ? bk : bv;
        const float* bsB = (selB == 0) ? bq : (selB == 1) ? bk : bv;
        const float scA = (selA == 1) ? LOG2E : 1.0f;
        const float scB = (selB == 1) ? LOG2E : 1.0f;

        float vA[4], vB[4];
#pragma unroll
        for (int j = 0; j < 4; ++j) {
            vA[j] = (acc[4 * gA + j] + bsA[hA * DQK + 4 * hp + j]) * scA;
            vB[j] = (acc[4 * gB + j] + bsB[hB * DQK + 4 * hp + j]) * scB;
        }
        const unsigned PA0 = pack2bf(vA[0], vA[1]), PA1 = pack2bf(vA[2], vA[3]);
        const unsigned PB0 = pack2bf(vB[0], vB[1]), PB1 = pack2bf(vB[2], vB[3]);

        const int s0 = hp ? (int)PA0 : (int)PB0;
        const int s1 = hp ? (int)PA1 : (int)PB1;
        const unsigned r0 = (unsigned)__shfl_xor(s0, 32, 64);
        const unsigned r1 = (unsigned)__shfl_xor(s1, 32, 64);

        const uint4 row = hp ? make_uint4(r0, r1, PB0, PB1)
                             : make_uint4(PA0, PA1, r0, r1);

        const unsigned offA = (selA == 0) ? Q_OFF : (selA == 1) ? K_OFF : VR_OFF;
        const unsigned offB = (selB == 0) ? Q_OFF : (selB == 1) ? K_OFF : VR_OFF;
        unsigned char* dA = ws + offA + ((size_t)(b * NH + hA) * NSP + n) * 16;
        unsigned char* dB = ws + offB + ((size_t)(b * NH + hB) * NSP + n) * 16;
        *(uint4*)(hp ? dB : dA) = row;
    }
}

// ---------------------------------------------------------------------------
// K1b: build PV B-fragments (+ones col e=8) from v rows. L1-hot u16 gathers.
// grid (128 T, 8 bh), block 64 (36 active lanes).
// ---------------------------------------------------------------------------
__global__ __launch_bounds__(64) void vfrag_kernel(unsigned char* __restrict__ ws)
{
    const int tid = threadIdx.x;
    if (tid >= 36) return;
    const int T = blockIdx.x;
    const int bh = blockIdx.y;
    const int e = tid % 9;
    const int r = tid / 9;        // 0..3
    const int h2 = r & 1, c2 = r >> 1;

    unsigned char* dst = ws + VF_OFF + (size_t)bh * 262144u +
                         (size_t)((T * 2 + c2) * 64 + 32 * h2 + e) * 16;
    if (e == 8) {
        *(uint4*)dst = make_uint4(0x3F803F80u, 0x3F803F80u, 0x3F803F80u, 0x3F803F80u);
        return;
    }
    const unsigned char* src = ws + VR_OFF +
        ((size_t)bh * NSP + T * 32 + c2 * 16 + h2 * 8) * 16 + e * 2;
    unsigned w0 = 0, w1 = 0, w2 = 0, w3 = 0;
    w0 = (unsigned)*(const unsigned short*)(src + 0 * 16) |
         ((unsigned)*(const unsigned short*)(src + 1 * 16) << 16);
    w1 = (unsigned)*(const unsigned short*)(src + 2 * 16) |
         ((unsigned)*(const unsigned short*)(src + 3 * 16) << 16);
    w2 = (unsigned)*(const unsigned short*)(src + 4 * 16) |
         ((unsigned)*(const unsigned short*)(src + 5 * 16) << 16);
    w3 = (unsigned)*(const unsigned short*)(src + 6 * 16) |
         ((unsigned)*(const unsigned short*)(src + 7 * 16) << 16);
    *(uint4*)dst = make_uint4(w0, w1, w2, w3);
}

// ---------------------------------------------------------------------------
// K2: MFMA flash attention (transposed softmax), partial over n-quarters.
// 1 wave per (m-tile, bh, nq): grid (128, 8, 4). Barrier-free, LDS-free.
// ---------------------------------------------------------------------------
__global__ __launch_bounds__(64, 4) void attn_partial(unsigned char* __restrict__ ws)
{
    const int lane = threadIdx.x;
    const int mt = blockIdx.x;   // 0..127
    const int bh = blockIdx.y;   // 0..7
    const int nq = blockIdx.z;   // 0..3
    const int e = lane & 31;
    const int hp = lane >> 5;

    union U4 { uint4 u; short8 s; };
    const uint4 zero4 = make_uint4(0, 0, 0, 0);

    U4 kf;
    kf.u = (hp == 0)
        ? *(const uint4*)(ws + K_OFF + ((size_t)bh * NSP + mt * 32 + e) * 16)
        : zero4;

    const uint4* qrows = (const uint4*)(ws + Q_OFF + (size_t)bh * NSP * 16);
    const uint4* vfr = (const uint4*)(ws + VF_OFF + (size_t)bh * 262144u);

    f32x16 acc = {};
    const f32x16 zc = {};

    const int nt0 = nq * 32;
    U4 qf_n, vf0_n, vf1_n;
    qf_n.u = (hp == 0) ? qrows[nt0 * 32 + e] : zero4;
    vf0_n.u = vfr[(nt0 * 2 + 0) * 64 + lane];
    vf1_n.u = vfr[(nt0 * 2 + 1) * 64 + lane];

    for (int t = 0; t < 32; ++t) {
        U4 qf = qf_n, vf0 = vf0_n, vf1 = vf1_n;
        if (t < 31) {  // software prefetch next tile
            const int nt = nt0 + t + 1;
            qf_n.u = (hp == 0) ? qrows[nt * 32 + e] : zero4;
            vf0_n.u = vfr[(nt * 2 + 0) * 64 + lane];
            vf1_n.u = vfr[(nt * 2 + 1) * 64 + lane];
        }

        // S^T[n,m]: lane holds col m, 16 rows n
        f32x16 S = __builtin_amdgcn_mfma_f32_32x32x16_bf16(qf.s, kf.s, zc, 0, 0, 0);

        // exp2 (k pre-scaled by log2e) + truncation-pack to bf16
        unsigned Qd[8];
#pragma unroll
        for (int i = 0; i < 8; ++i) {
            const float a = fast_exp2(S[2 * i]);
            const float b2 = fast_exp2(S[2 * i + 1]);
            Qd[i] = pack2bf_tr(a, b2);
        }

        // xor-32 exchange: build A-layout frags (rows m, k=n)
        const int sA0 = hp ? Qd[0] : Qd[2];
        const int sA1 = hp ? Qd[1] : Qd[3];
        const int rA0 = __shfl_xor(sA0, 32, 64);
        const int rA1 = __shfl_xor(sA1, 32, 64);
        const int sB0 = hp ? Qd[4] : Qd[6];
        const int sB1 = hp ? Qd[5] : Qd[7];
        const int rB0 = __shfl_xor(sB0, 32, 64);
        const int rB1 = __shfl_xor(sB1, 32, 64);

        U4 f0, f1;
        f0.u = hp ? make_uint4(rA0, rA1, Qd[2], Qd[3])
                  : make_uint4(Qd[0], Qd[1], rA0, rA1);
        f1.u = hp ? make_uint4(rB0, rB1, Qd[6], Qd[7])
                  : make_uint4(Qd[4], Qd[5], rB0, rB1);

        acc = __builtin_amdgcn_mfma_f32_32x32x16_bf16(f0.s, vf0.s, acc, 0, 0, 0);
        acc = __builtin_amdgcn_mfma_f32_32x32x16_bf16(f1.s, vf1.s, acc, 0, 0, 0);
    }

    if (e <= 8) {
        float* pp = (float*)(ws + P_OFF) +
                    ((((size_t)bh * 128 + mt) * 4 + nq) * 18 + hp * 9 + e) * 16;
#pragma unroll
        for (int r = 0; r < 16; ++r) pp[r] = acc[r];
    }
}

// ---------------------------------------------------------------------------
// K3: epilogue. Sum 4 n-quarter partials, normalize, Wo+bias+gamma+residual.
// ---------------------------------------------------------------------------
__global__ __launch_bounds__(256) void attn_epilogue(
    const unsigned char* __restrict__ ws,
    const float* __restrict__ x,
    const float* __restrict__ Wo, const float* __restrict__ bo,
    const float* __restrict__ gamma,
    float* __restrict__ out)
{
    __shared__ float sO[128 * 13];
    const int tid = threadIdx.x;
    const int ms = blockIdx.x;   // 0..31
    const int bh = blockIdx.y;   // 0..7
    const int h = bh & (NH - 1);
    const int b = bh >> 2;

    const float* P = (const float*)(ws + P_OFF);
    for (int idx = tid; idx < 128 * 9; idx += 256) {
        const int m_l = idx / 9, e = idx % 9;
        const int mt = ms * 4 + (m_l >> 5);
        const int m32 = m_l & 31;
        const int hp = (m32 >> 2) & 1;
        const int r = (m32 & 3) + 4 * (m32 >> 3);
        const size_t base = ((((size_t)bh * 128 + mt) * 4) * 18 + hp * 9 + e) * 16 + r;
        const float s = P[base] + P[base + 18 * 16] +
                        P[base + 2 * 18 * 16] + P[base + 3 * 18 * 16];
        sO[m_l * 13 + e] = s;
    }
    __syncthreads();

    const int m_l = tid & 127;
    const int half = tid >> 7;
    const float rl = 1.0f / sO[m_l * 13 + 8];
    float od[DQK];
#pragma unroll
    for (int d = 0; d < DQK; ++d) od[d] = sO[m_l * 13 + d] * rl;

    const float g = gamma[h];
    const int mg = ms * 128 + m_l;
#pragma unroll
    for (int eo = half * 32; eo < half * 32 + 32; ++eo) {
        const float* wo = Wo + (h * ATH + eo) * DQK;
        float y = bo[h * ATH + eo];
#pragma unroll
        for (int d = 0; d < DQK; ++d) y = fmaf(wo[d], od[d], y);
        const size_t oi = ((size_t)(b * IN_DIM) + h * ATH + eo) * NSP + mg;
        out[oi] = fmaf(g, y, x[oi]);
    }
}

extern "C" void kernel_launch(void* const* d_in, const int* in_sizes, int n_in,
                              void* d_out, int out_size, void* d_ws, size_t ws_size,
                              hipStream_t stream)
{
    const float* x = (const float*)d_in[0];
    const float* Wq = (const float*)d_in[1];
    const float* bq = (const float*)d_in[2];
    const float* Wk = (const float*)d_in[3];
    const float* bk = (const float*)d_in[4];
    const float* Wv = (const float*)d_in[5];
    const float* bv = (const float*)d_in[6];
    const float* Wo = (const float*)d_in[7];
    const float* bo = (const float*)d_in[8];
    const float* gamma = (const float*)d_in[9];
    float* out = (float*)d_out;
    unsigned char* ws = (unsigned char*)d_ws;  // uses ~8.2 MB

    qkv_gemm<<<dim3(128, 3, NB), 64, 0, stream>>>(
        x, Wq, bq, Wk, bk, Wv, bv, ws);
    vfrag_kernel<<<dim3(128, NB * NH), 64, 0, stream>>>(ws);
    attn_partial<<<dim3(128, NB * NH, 4), 64, 0, stream>>>(ws);
    attn_epilogue<<<dim3(32, NB * NH), 256, 0, stream>>>(
        ws, x, Wo, bo, gamma, out);
}